// Round 8
// baseline (38456.223 us; speedup 1.0000x reference)
//
#include <hip/hip_runtime.h>

// LSTM(H=1024) over SEQ=8192, input_size=1 — round 8: wave-specialized,
// barrier-free persistent kernel. 128 wgs x 640 threads (10 waves):
//   waves 0-7: compute. Wave w owns h-index j=8g+w (4 gate rows of W_hh in
//              64 AGPRs/thread, volatile accvgpr pin — proven resident r5/r7).
//              They never read global: they spin on an LDS versioned chunk-mask
//              (~20cy sampling vs ~900cy MALL RT) and FMA chunk-by-chunk, so
//              compute on early chunks overlaps polling of stragglers.
//   wave 8:    poller. Sole global reader: polls 1024 (tag,h) 8B slots
//              (16/lane, batched in-flight loads), stages arrived 64-h chunks
//              into double-buffered LDS, release-stores mask=(t<<16)|bits.
//   wave 9:    out-wave (wg 0 only): computes out[t]=W_lin.h_t+b_lin from the
//              staged LDS h — out[] written completely here; no init/finish
//              kernels, no partials. Single kernel launch.
// No __syncthreads in the main loop. Cross-wg protocol: (tag,h) packed 8B
// slots, double-buffered, relaxed agent-scope atomics; distance-2 reuse
// safety: a publish of tag t+1 implies every wg's poller finished step t-1.

#define SEQ 8192
#define HID 1024
#define NWG 128
#define TPB 640
#define NCW 8

typedef unsigned long long ull;

__device__ __forceinline__ float fast_sigmoid(float z) {
    float e = __builtin_amdgcn_exp2f(-1.4426950408889634f * z);
    return 1.0f / (1.0f + e);
}
__device__ __forceinline__ float fast_tanh(float x) {
    float e = __builtin_amdgcn_exp2f(2.8853900817779268f * x);
    return 1.0f - 2.0f / (e + 1.0f);
}

__global__ __launch_bounds__(TPB, 2)
void lstm_kernel(const float* __restrict__ sentence,
                 const float* __restrict__ W_ih,
                 const float* __restrict__ W_hh,
                 const float* __restrict__ b_ih,
                 const float* __restrict__ b_hh,
                 const float* __restrict__ W_lin,
                 const float* __restrict__ b_lin,
                 ull* slots, float* out)
{
    __shared__ float s_sent[SEQ];       // 32 KiB: whole input, read once
    __shared__ float s_h[2][HID];       // double-buffered staged h
    __shared__ unsigned s_mask[2];      // versioned chunk masks: (t<<16)|bits
    const int tid = threadIdx.x;
    const int g = blockIdx.x;
    const int w = tid >> 6;
    const int l = tid & 63;

    for (int i = tid; i < SEQ; i += TPB) s_sent[i] = sentence[i];
    if (tid < 2) s_mask[tid] = 0u;
    for (int i = tid; i < 2 * HID; i += TPB) ((float*)s_h)[i] = 0.0f;

    // ---- per-role setup ----
    float Wa[4][16];                    // compute: W_hh rows in AGPRs
    float wih[4], bb[4];
    float wl[16];                       // out-wave: W_lin slice
    float blin = 0.0f;
    float wdummy = 0.0f;
    if (w < NCW) {
        const int j = g * NCW + w;
        #pragma unroll
        for (int gate = 0; gate < 4; ++gate) {
            const float* rowp = W_hh + (size_t)(j + gate * HID) * HID;
            #pragma unroll
            for (int k = 0; k < 16; ++k) {
                float tmp = rowp[k * 64 + l];
                asm volatile("v_accvgpr_write_b32 %0, %1" : "=a"(Wa[gate][k]) : "v"(tmp));
            }
        }
        #pragma unroll
        for (int gate = 0; gate < 4; ++gate) {
            int row = j + gate * HID;
            wih[gate] = W_ih[row];
            bb[gate]  = b_ih[row] + b_hh[row];
        }
    } else if (w == NCW + 1) {
        #pragma unroll
        for (int k = 0; k < 16; ++k) wl[k] = W_lin[k * 64 + l];
        blin = b_lin[0];
    }
    (void)wdummy;
    __syncthreads();   // only barrier: staging + setup complete

    if (w < NCW) {
        // ======================= compute waves =======================
        const int j = g * NCW + w;
        float c = 0.0f;
        for (int t = 0; t < SEQ; ++t) {
            const int p = t & 1;
            float a0 = 0.f, a1 = 0.f, a2 = 0.f, a3 = 0.f;
            if (t > 0) {
                const unsigned tt = (unsigned)t;
                unsigned have = 0u;
                int guard = 0;
                #pragma unroll
                for (int k = 0; k < 16; ++k) {
                    while (!((have >> k) & 1u)) {
                        unsigned mv = __hip_atomic_load(&s_mask[p], __ATOMIC_ACQUIRE,
                                                        __HIP_MEMORY_SCOPE_WORKGROUP);
                        have = ((mv >> 16) == tt) ? (mv & 0xFFFFu) : 0u;
                        if (++guard > (1 << 22)) have = 0xFFFFu;  // fail loud
                    }
                    const float hk = s_h[p][k * 64 + l];
                    float w0, w1, w2, w3;
                    asm volatile("v_accvgpr_read_b32 %0, %1" : "=v"(w0) : "a"(Wa[0][k]));
                    asm volatile("v_accvgpr_read_b32 %0, %1" : "=v"(w1) : "a"(Wa[1][k]));
                    asm volatile("v_accvgpr_read_b32 %0, %1" : "=v"(w2) : "a"(Wa[2][k]));
                    asm volatile("v_accvgpr_read_b32 %0, %1" : "=v"(w3) : "a"(Wa[3][k]));
                    a0 = fmaf(w0, hk, a0);
                    a1 = fmaf(w1, hk, a1);
                    a2 = fmaf(w2, hk, a2);
                    a3 = fmaf(w3, hk, a3);
                }
            }
            #pragma unroll
            for (int m = 1; m < 64; m <<= 1) {
                a0 += __shfl_xor(a0, m, 64);
                a1 += __shfl_xor(a1, m, 64);
                a2 += __shfl_xor(a2, m, 64);
                a3 += __shfl_xor(a3, m, 64);
            }
            const float x = s_sent[t];
            float zi = fmaf(wih[0], x, a0 + bb[0]);
            float zf = fmaf(wih[1], x, a1 + bb[1]);
            float zg = fmaf(wih[2], x, a2 + bb[2]);
            float zo = fmaf(wih[3], x, a3 + bb[3]);
            c = fmaf(fast_sigmoid(zf), c, fast_sigmoid(zi) * fast_tanh(zg));
            const float hn = fast_sigmoid(zo) * fast_tanh(c);
            if (l == 0) {
                ull pk = ((ull)(unsigned)(t + 1) << 32) | (ull)__float_as_uint(hn);
                __hip_atomic_store(&slots[(size_t)(((t + 1) & 1)) * HID + j], pk,
                                   __ATOMIC_RELAXED, __HIP_MEMORY_SCOPE_AGENT);
                asm volatile("" ::: "memory");
            }
        }
    } else if (w == NCW) {
        // ========================= poller wave =======================
        for (int t = 1; t <= SEQ; ++t) {
            const int p = t & 1;
            const unsigned tt = (unsigned)t;
            ull* bg = slots + (size_t)p * HID;
            unsigned pend = 0xFFFFu, mask = 0u;
            int guard = 0;
            while (pend) {
                ull v[16];
                #pragma unroll
                for (int k = 0; k < 16; ++k)
                    if ((pend >> k) & 1u)
                        v[k] = __hip_atomic_load(&bg[k * 64 + l], __ATOMIC_RELAXED,
                                                 __HIP_MEMORY_SCOPE_AGENT);
                unsigned newly = 0u;
                #pragma unroll
                for (int k = 0; k < 16; ++k)
                    if ((pend >> k) & 1u)
                        if (__all((int)((unsigned)(v[k] >> 32) == tt)))
                            newly |= (1u << k);
                if (newly) {
                    #pragma unroll
                    for (int k = 0; k < 16; ++k)
                        if ((newly >> k) & 1u)
                            s_h[p][k * 64 + l] = __uint_as_float((unsigned)v[k]);
                    mask |= newly;
                    pend &= ~newly;
                    if (l == 0)
                        __hip_atomic_store(&s_mask[p], (tt << 16) | mask,
                                           __ATOMIC_RELEASE, __HIP_MEMORY_SCOPE_WORKGROUP);
                }
                if (++guard > (1 << 20)) break;  // fail loud, don't hang
            }
        }
    } else if (g == 0) {
        // ===================== out-wave (wg 0 only) ==================
        for (int t = 1; t <= SEQ; ++t) {
            const int p = t & 1;
            const unsigned want = ((unsigned)t << 16) | 0xFFFFu;
            int guard = 0;
            while (__hip_atomic_load(&s_mask[p], __ATOMIC_ACQUIRE,
                                     __HIP_MEMORY_SCOPE_WORKGROUP) != want)
                if (++guard > (1 << 24)) break;  // fail loud
            float po = 0.f;
            #pragma unroll
            for (int k = 0; k < 16; ++k) po = fmaf(wl[k], s_h[p][k * 64 + l], po);
            #pragma unroll
            for (int m = 1; m < 64; m <<= 1) po += __shfl_xor(po, m, 64);
            if (l == 0) out[t - 1] = po + blin;
        }
    }
}

extern "C" void kernel_launch(void* const* d_in, const int* in_sizes, int n_in,
                              void* d_out, int out_size, void* d_ws, size_t ws_size,
                              hipStream_t stream) {
    const float* sentence = (const float*)d_in[0];
    const float* W_ih     = (const float*)d_in[1];
    const float* W_hh     = (const float*)d_in[2];
    const float* b_ih     = (const float*)d_in[3];
    const float* b_hh     = (const float*)d_in[4];
    const float* W_lin    = (const float*)d_in[5];
    const float* b_lin    = (const float*)d_in[6];
    float* out = (float*)d_out;

    // ws: 2 x 1024 x 8B tagged h slots. No init needed: poisoned tag
    // 0xAAAAAAAA never matches a live tag (1..SEQ), and out[] is fully
    // written by the wg-0 out-wave every launch.
    ull* slots = (ull*)d_ws;

    hipLaunchKernelGGL(lstm_kernel, dim3(NWG), dim3(TPB), 0, stream,
                       sentence, W_ih, W_hh, b_ih, b_hh, W_lin, b_lin,
                       slots, out);
}

// Round 9
// 34569.891 us; speedup vs baseline: 1.1124x; 1.1124x over previous
//
#include <hip/hip_runtime.h>

// LSTM(H=1024) over SEQ=8192, input_size=1 — round 9.
// r2's proven-best minimal sync structure, unchanged:
//   (tag,h) packed 8B slots, double-buffered; per-thread TIGHT unconditional
//   poll (two back-to-back 8B agent-scope loads, both in flight, ONE RT,
//   no branchy early-exit — r7 proved the branchy poll regresses 5ms);
//   stage to LDS; one __syncthreads; compute; fire-and-forget publish.
// Plus the one delta r2 lacked: W_hh register-resident in 64 AGPRs/thread
// via VOLATILE v_accvgpr_write/read (r5/r7/r8 proved this form stays
// resident, no scratch) — shortens the exposed compute tail after the last
// h arrives. Poll pairs are ADJACENT slots {2tid,2tid+1} (same MALL line;
// LDS writes merge to ds_write_b64).
// 128 wgs x 512 threads (1 wg/CU), wave w of wg g owns h-index j=8g+w.

#define SEQ 8192
#define HID 1024
#define NWG 128
#define TPB 512
#define NWAVE 8

typedef unsigned long long ull;

__device__ __forceinline__ float fast_sigmoid(float z) {
    float e = __builtin_amdgcn_exp2f(-1.4426950408889634f * z);
    return 1.0f / (1.0f + e);
}
__device__ __forceinline__ float fast_tanh(float x) {
    float e = __builtin_amdgcn_exp2f(2.8853900817779268f * x);
    return 1.0f - 2.0f / (e + 1.0f);
}

// ws/out re-poisoned 0xAA each launch. Slots need no init (poison tag
// 0xAAAAAAAA never equals a live tag 1..SEQ; tags strictly increase within a
// launch). out[] prefilled with b_lin; partials fully overwritten per launch.
__global__ void init_kernel(float* out, const float* __restrict__ b_lin) {
    int i = blockIdx.x * blockDim.x + threadIdx.x;
    if (i < SEQ) out[i] = b_lin[0];
}

__global__ void finish_kernel(const float* __restrict__ partials,
                              float* __restrict__ out) {
    int t = blockIdx.x * blockDim.x + threadIdx.x;
    if (t >= SEQ) return;
    float s = out[t];  // b_lin from init
    #pragma unroll 4
    for (int g2 = 0; g2 < NWG; ++g2) s += partials[(size_t)g2 * SEQ + t];
    out[t] = s;
}

__global__ __launch_bounds__(TPB, 2)
void lstm_kernel(const float* __restrict__ sentence,
                 const float* __restrict__ W_ih,
                 const float* __restrict__ W_hh,
                 const float* __restrict__ b_ih,
                 const float* __restrict__ b_hh,
                 const float* __restrict__ W_lin,
                 ull* slots, float* partials, float* out, int use_partials)
{
    __shared__ float s_sent[SEQ];      // 32 KiB: whole input, read once
    __shared__ float s_h[HID];         // staged h_{t-1}
    __shared__ float s_part[2][NWAVE]; // per-wave W_lin partials, dbuf'd
    const int tid = threadIdx.x;
    const int g = blockIdx.x;
    const int w = tid >> 6;
    const int l = tid & 63;
    const int j = g * NWAVE + w;       // this wave's h-index (0..1023)

    for (int i = tid; i < SEQ; i += TPB) s_sent[i] = sentence[i];

    // 4 gate rows of W_hh into 64 AGPRs/thread. Lane l holds columns
    // {k*64+l : k=0..15} of each row. Volatile write AND read => regalloc can
    // neither spill nor hoist (r3's non-volatile reads were hoisted->spill).
    float Wa[4][16];
    #pragma unroll
    for (int gate = 0; gate < 4; ++gate) {
        const float* rowp = W_hh + (size_t)(j + gate * HID) * HID;
        #pragma unroll
        for (int k = 0; k < 16; ++k) {
            float tmp = rowp[k * 64 + l];
            asm volatile("v_accvgpr_write_b32 %0, %1" : "=a"(Wa[gate][k]) : "v"(tmp));
        }
    }
    float wih[4], bb[4];
    #pragma unroll
    for (int gate = 0; gate < 4; ++gate) {
        int row = j + gate * HID;
        wih[gate] = W_ih[row];
        bb[gate]  = b_ih[row] + b_hh[row];
    }
    const float wlin = W_lin[j];
    float c = 0.0f;

    ull* const buf0 = slots;           // 1024 slots x 8B per buffer
    ull* const buf1 = slots + HID;

    __syncthreads();  // sentence staged

    for (int t = 0; t < SEQ; ++t) {
        // ---- acquire h_{t-1}: tight unconditional 2-load poll (r2 form) ----
        if (t == 0) {
            s_h[2 * tid]     = 0.0f;
            s_h[2 * tid + 1] = 0.0f;
        } else {
            ull* b = (t & 1) ? buf1 : buf0;
            const unsigned tt = (unsigned)t;
            ull v0, v1;
            int guard = 0;
            for (;;) {
                v0 = __hip_atomic_load(&b[2 * tid],     __ATOMIC_RELAXED, __HIP_MEMORY_SCOPE_AGENT);
                v1 = __hip_atomic_load(&b[2 * tid + 1], __ATOMIC_RELAXED, __HIP_MEMORY_SCOPE_AGENT);
                if ((unsigned)(v0 >> 32) == tt && (unsigned)(v1 >> 32) == tt) break;
                if (++guard > (1 << 24)) break;  // fail loud, don't hang
            }
            s_h[2 * tid]     = __uint_as_float((unsigned)v0);
            s_h[2 * tid + 1] = __uint_as_float((unsigned)v1);
        }
        __syncthreads();

        // Drain previous step's output partial (post-barrier => s_part[t-1]
        // complete; one thread, off the critical path).
        if (t > 0 && tid == 0) {
            const float* sp = s_part[(t - 1) & 1];
            float p = sp[0] + sp[1] + sp[2] + sp[3] + sp[4] + sp[5] + sp[6] + sp[7];
            if (use_partials) partials[(size_t)g * SEQ + (t - 1)] = p;
            else atomicAdd(&out[t - 1], p);
        }

        // ---- z = W_hh[rows of j] . h (wave-wide, W from AGPRs) ----
        float acc0 = 0.f, acc1 = 0.f, acc2 = 0.f, acc3 = 0.f;
        #pragma unroll
        for (int k = 0; k < 16; ++k) {
            const float hk = s_h[k * 64 + l];
            float w0, w1, w2, w3;
            asm volatile("v_accvgpr_read_b32 %0, %1" : "=v"(w0) : "a"(Wa[0][k]));
            asm volatile("v_accvgpr_read_b32 %0, %1" : "=v"(w1) : "a"(Wa[1][k]));
            asm volatile("v_accvgpr_read_b32 %0, %1" : "=v"(w2) : "a"(Wa[2][k]));
            asm volatile("v_accvgpr_read_b32 %0, %1" : "=v"(w3) : "a"(Wa[3][k]));
            acc0 = fmaf(w0, hk, acc0);
            acc1 = fmaf(w1, hk, acc1);
            acc2 = fmaf(w2, hk, acc2);
            acc3 = fmaf(w3, hk, acc3);
        }
        #pragma unroll
        for (int m = 1; m < 64; m <<= 1) {
            acc0 += __shfl_xor(acc0, m, 64);
            acc1 += __shfl_xor(acc1, m, 64);
            acc2 += __shfl_xor(acc2, m, 64);
            acc3 += __shfl_xor(acc3, m, 64);
        }

        const float x = s_sent[t];
        float zi = fmaf(wih[0], x, acc0 + bb[0]);
        float zf = fmaf(wih[1], x, acc1 + bb[1]);
        float zg = fmaf(wih[2], x, acc2 + bb[2]);
        float zo = fmaf(wih[3], x, acc3 + bb[3]);
        c = fmaf(fast_sigmoid(zf), c, fast_sigmoid(zi) * fast_tanh(zg));
        const float hn = fast_sigmoid(zo) * fast_tanh(c);

        // ---- publish (tag=t+1, h_t[j]) — one 8B store, fire-and-forget ----
        if (l == 0) {
            ull pk = ((ull)(unsigned)(t + 1) << 32) | (ull)__float_as_uint(hn);
            __hip_atomic_store(&(((t + 1) & 1) ? buf1 : buf0)[j], pk,
                               __ATOMIC_RELAXED, __HIP_MEMORY_SCOPE_AGENT);
            asm volatile("" ::: "memory");
            s_part[t & 1][w] = wlin * hn;
        }
        // No trailing barrier: distance-2 buffer-reuse safety (publishing
        // tag t+1 implies this wg observed ALL step-t tags, i.e. every wg is
        // past step t-1's reads of the buffer being overwritten).
    }

    __syncthreads();
    if (tid == 0) {  // final step's output partial
        const float* sp = s_part[(SEQ - 1) & 1];
        float p = sp[0] + sp[1] + sp[2] + sp[3] + sp[4] + sp[5] + sp[6] + sp[7];
        if (use_partials) partials[(size_t)g * SEQ + (SEQ - 1)] = p;
        else atomicAdd(&out[SEQ - 1], p);
    }
}

extern "C" void kernel_launch(void* const* d_in, const int* in_sizes, int n_in,
                              void* d_out, int out_size, void* d_ws, size_t ws_size,
                              hipStream_t stream) {
    const float* sentence = (const float*)d_in[0];
    const float* W_ih     = (const float*)d_in[1];
    const float* W_hh     = (const float*)d_in[2];
    const float* b_ih     = (const float*)d_in[3];
    const float* b_hh     = (const float*)d_in[4];
    const float* W_lin    = (const float*)d_in[5];
    const float* b_lin    = (const float*)d_in[6];
    float* out = (float*)d_out;

    char* ws = (char*)d_ws;
    ull* slots      = (ull*)ws;                          // 16 KiB (2 x 1024 x 8B)
    float* partials = (float*)(ws + 2 * HID * sizeof(ull));
    const size_t need = 2 * HID * sizeof(ull) + (size_t)NWG * SEQ * sizeof(float);
    int use_partials = (ws_size >= need) ? 1 : 0;        // fallback: atomicAdd

    hipLaunchKernelGGL(init_kernel, dim3(SEQ / 256), dim3(256), 0, stream,
                       out, b_lin);
    hipLaunchKernelGGL(lstm_kernel, dim3(NWG), dim3(TPB), 0, stream,
                       sentence, W_ih, W_hh, b_ih, b_hh, W_lin,
                       slots, partials, out, use_partials);
    if (use_partials) {
        hipLaunchKernelGGL(finish_kernel, dim3(SEQ / 256), dim3(256), 0, stream,
                           partials, out);
    }
}